// Round 14
// baseline (345.077 us; speedup 1.0000x reference)
//
#include <hip/hip_runtime.h>
#include <math.h>

#define N_NODES 50000
#define E_EDGES 1600000
#define IN_CH   34
#define NEG     0.2f
#define NB      196          // coarse buckets: dst>>8
#define CAP     10000        // bucket capacity (E[8163], sigma~90)
#define EPB     8192         // edges per bin block (%4==0)
#define NBB     196          // ceil(E_EDGES / EPB)
#define GNPB    96           // GEMM-role nodes per block (768 thr, 4 rows/thread)

typedef __attribute__((ext_vector_type(2))) float fv2;

static __device__ __forceinline__ unsigned short f2bf(float f) {
    unsigned int u = __float_as_uint(f);
    u += 0x7fffu + ((u >> 16) & 1u);
    return (unsigned short)(u >> 16);
}
static __device__ __forceinline__ float bflo(unsigned int u) {
    return __uint_as_float(u << 16);
}
static __device__ __forceinline__ float bfhi(unsigned int u) {
    return __uint_as_float(u & 0xffff0000u);
}
static __device__ __forceinline__ float lrelu_exp(float e) {
    return __expf(e > 0.f ? e : NEG * e);   // v_exp_f32 path, not libm
}

// Exclusive scan over 256 values held by the first 256 threads of a block
// with >=256 threads (all threads must call; contains barriers).
static __device__ __forceinline__ int scan256_wide(int v, int* wsum) {
    const int lane = threadIdx.x & 63, wv = threadIdx.x >> 6;
    int x = v;
    #pragma unroll
    for (int off = 1; off < 64; off <<= 1) {
        int y = __shfl_up(x, off);
        if (lane >= off) x += y;
    }
    if (wv < 4 && lane == 63) wsum[wv] = x;
    __syncthreads();
    if (threadIdx.x < 4) {
        int s = wsum[threadIdx.x];
        #pragma unroll
        for (int off = 1; off < 4; off <<= 1) {
            int y = __shfl_up(s, off);
            if ((int)threadIdx.x >= off) s += y;
        }
        wsum[threadIdx.x] = s;
    }
    __syncthreads();
    const int woff = (wv >= 1 && wv < 4) ? wsum[wv - 1] : 0;
    return woff + x - v;
}

// ---------------------------------------------------------------------------
// Fused, 768 threads, __launch_bounds__(768,1): explicit min-occupancy of 1
// block/CU (12 waves -> 3 waves/SIMD) caps VGPR at >=170 under BOTH possible
// semantics of the 2nd arg (r12 proved the arg is honored exactly; r5/r12/r13
// showed wide launches without it get 64 and spill). The r10 GEMM role
// (136 VGPR) fits unmodified; the bin role gets 12 waves (r4/r6: waves/block
// is the lever that shortens the LDS-atomic chain: 4w~55us, 16w~28us/block).
// Blocks [0,NBB) bin 8192 edges; blocks [NBB,..) GEMM 96 nodes each.
// gcur must be zeroed beforehand.
// ---------------------------------------------------------------------------
__global__ __launch_bounds__(768, 1) void k_bin_node1(
    const int* __restrict__ srcA, const int* __restrict__ dstA,
    int* __restrict__ gcur, unsigned int* __restrict__ binned,
    const float* __restrict__ x, const float* __restrict__ W1,
    const float* __restrict__ a_src, const float* __restrict__ a_dst,
    unsigned short* __restrict__ xw1b,
    float* __restrict__ al_s, float* __restrict__ al_d)
{
    __shared__ __align__(16) char sm[69664];
    const int tid = threadIdx.x;

    if (blockIdx.x < NBB) {
        // ---- binning role (12 waves, r10 phases) ----
        unsigned int* raw  = (unsigned int*)sm;            // 32768 B
        unsigned int* ebuf = (unsigned int*)(sm + 32768);  // 32768 B
        int* cnt  = (int*)(sm + 65536);
        int* loff = (int*)(sm + 66560);
        int* lcur = (int*)(sm + 67584);
        int* cur  = (int*)(sm + 68608);
        int* wsum = (int*)(sm + 69632);
        if (tid < 256) cnt[tid] = 0;
        __syncthreads();
        const int base = blockIdx.x * EPB;
        const int mE = min(EPB, E_EDGES - base);           // %4 == 0
        const int nq = mE >> 2;
        for (int q = tid; q < nq; q += 768) {
            const int4 d4 = ((const int4*)(dstA + base))[q];
            const int4 s4 = ((const int4*)(srcA + base))[q];
            raw[4 * q + 0] = ((unsigned)d4.x << 16) | (unsigned)s4.x;
            raw[4 * q + 1] = ((unsigned)d4.y << 16) | (unsigned)s4.y;
            raw[4 * q + 2] = ((unsigned)d4.z << 16) | (unsigned)s4.z;
            raw[4 * q + 3] = ((unsigned)d4.w << 16) | (unsigned)s4.w;
            atomicAdd(&cnt[d4.x >> 8], 1);
            atomicAdd(&cnt[d4.y >> 8], 1);
            atomicAdd(&cnt[d4.z >> 8], 1);
            atomicAdd(&cnt[d4.w >> 8], 1);
        }
        __syncthreads();
        const int v = (tid < 256) ? cnt[tid] : 0;
        const int excl = scan256_wide(v, wsum);
        if (tid < 256) { loff[tid] = excl; lcur[tid] = excl; }
        if (tid < NB) cur[tid] = (v > 0) ? (tid * CAP + atomicAdd(&gcur[tid], v)) : 0;
        __syncthreads();
        for (int p = tid; p < mE; p += 768) {
            const unsigned int u = raw[p];
            const int q = atomicAdd(&lcur[u >> 24], 1);
            ebuf[q] = u;
        }
        __syncthreads();
        for (int p = tid; p < mE; p += 768) {
            const unsigned int u = ebuf[p];
            const int b = (int)(u >> 24);
            binned[cur[b] + (p - loff[b])] = u;
        }
    } else {
        // ---- node1 role: xw1b = bf16(x @ W1), logits (96 nodes, acc[4][4]) ----
        float* sW  = (float*)sm;                 // 34*132*4 = 17952 B
        float* sx  = (float*)(sm + 17952);       // 96*36*4  = 13824 B
        float* sas = (float*)(sm + 31776);       // 512 B
        float* sad = (float*)(sm + 32288);       // 512 B -> 32800 total
        for (int i = tid; i < IN_CH * 128; i += 768) {
            int k = i >> 7, c = i & 127;
            sW[k * 132 + c] = W1[i];
        }
        if (tid < 128) { sas[tid] = a_src[tid]; sad[tid] = a_dst[tid]; }
        const int n0 = (blockIdx.x - NBB) * GNPB;
        for (int i = tid; i < GNPB * IN_CH; i += 768) {
            int n = i / IN_CH;
            sx[n * 36 + (i - n * IN_CH)] = (n0 + n < N_NODES) ? x[n0 * IN_CH + i] : 0.f;
        }
        __syncthreads();

        const int tc = tid & 31, tn = tid >> 5;   // tn in [0,24): 96 rows
        float acc[4][4] = {{0.f}};
        int k = 0;
        for (; k + 4 <= IN_CH; k += 4) {
            const float4 w0 = *reinterpret_cast<const float4*>(&sW[(k + 0) * 132 + 4 * tc]);
            const float4 w1 = *reinterpret_cast<const float4*>(&sW[(k + 1) * 132 + 4 * tc]);
            const float4 w2 = *reinterpret_cast<const float4*>(&sW[(k + 2) * 132 + 4 * tc]);
            const float4 w3 = *reinterpret_cast<const float4*>(&sW[(k + 3) * 132 + 4 * tc]);
            #pragma unroll
            for (int j = 0; j < 4; ++j) {
                const float4 h4 = *reinterpret_cast<const float4*>(&sx[(4 * tn + j) * 36 + k]);
                acc[j][0] += h4.x * w0.x + h4.y * w1.x + h4.z * w2.x + h4.w * w3.x;
                acc[j][1] += h4.x * w0.y + h4.y * w1.y + h4.z * w2.y + h4.w * w3.y;
                acc[j][2] += h4.x * w0.z + h4.y * w1.z + h4.z * w2.z + h4.w * w3.z;
                acc[j][3] += h4.x * w0.w + h4.y * w1.w + h4.z * w2.w + h4.w * w3.w;
            }
        }
        for (; k < IN_CH; ++k) {
            const float4 wv = *reinterpret_cast<const float4*>(&sW[k * 132 + 4 * tc]);
            #pragma unroll
            for (int j = 0; j < 4; ++j) {
                const float hj = sx[(4 * tn + j) * 36 + k];
                acc[j][0] += hj * wv.x; acc[j][1] += hj * wv.y;
                acc[j][2] += hj * wv.z; acc[j][3] += hj * wv.w;
            }
        }
        #pragma unroll
        for (int j = 0; j < 4; ++j) {
            const int node = n0 + 4 * tn + j;
            float ps = 0.f, pd = 0.f;
            #pragma unroll
            for (int c = 0; c < 4; ++c) {
                ps += acc[j][c] * sas[4 * tc + c];
                pd += acc[j][c] * sad[4 * tc + c];
            }
            #pragma unroll
            for (int off = 1; off < 16; off <<= 1) {
                ps += __shfl_xor(ps, off);
                pd += __shfl_xor(pd, off);
            }
            if (node < N_NODES) {
                if ((tc & 15) == 0) {
                    int h = tc >> 4;
                    al_s[node * 2 + h] = ps;
                    al_d[node * 2 + h] = pd;
                }
                ushort4 u;
                u.x = f2bf(acc[j][0]); u.y = f2bf(acc[j][1]);
                u.z = f2bf(acc[j][2]); u.w = f2bf(acc[j][3]);
                *reinterpret_cast<ushort4*>(&xw1b[node * 128 + 4 * tc]) = u;
            }
        }
    }
}

// ---------------------------------------------------------------------------
// Per-bucket fine sort (LDS-staged) -> sorted_src + rowspan.
// 1024 threads (16 waves, 4/SIMD) hide the LDS-atomic latency chains.
// ---------------------------------------------------------------------------
__global__ __launch_bounds__(1024) void k_fine(
    const int* __restrict__ gcur, const unsigned int* __restrict__ binned,
    int2* __restrict__ rowspan, int* __restrict__ sorted_src)
{
    __shared__ unsigned int sbin[CAP];    // 40 KB
    __shared__ int cnt[256], lcur[256];
    __shared__ int wsum[4];
    const int tid = threadIdx.x;
    const int b = blockIdx.x;
    const int bbase = b * CAP;
    const int cntb = gcur[b];
    if (tid < 256) cnt[tid] = 0;
    __syncthreads();
    for (int p = tid; p < cntb; p += 1024) {
        const unsigned int u = binned[bbase + p];
        sbin[p] = u;
        atomicAdd(&cnt[(u >> 16) & 255], 1);
    }
    __syncthreads();
    const int v = (tid < 256) ? cnt[tid] : 0;
    const int excl = scan256_wide(v, wsum);
    if (tid < 256) {
        lcur[tid] = excl;
        const int node = b * 256 + tid;
        if (node < N_NODES) rowspan[node] = make_int2(bbase + excl, bbase + excl + v);
    }
    __syncthreads();
    for (int p = tid; p < cntb; p += 1024) {
        const unsigned int u = sbin[p];
        const int q = atomicAdd(&lcur[(u >> 16) & 255], 1);
        sorted_src[bbase + q] = (int)(u & 0xffffu);
    }
}

// ---------------------------------------------------------------------------
// Layer 1 gather: one wave per node; lane owns cols 2l,2l+1 (one uint/row).
// Per-head (offset,weight) pair-packed LDS arrays -> one ds_read_b128 per
// edge pair, no per-edge selects. fv2 accumulators (packed f32 fma).
// ---------------------------------------------------------------------------
__global__ __launch_bounds__(256) void k_gather1(
    const int2* __restrict__ rowspan, const int* __restrict__ sorted_src,
    const unsigned int* __restrict__ xw1u,    // 64 uints per row
    const float* __restrict__ al_s, const float* __restrict__ al_d,
    const float* __restrict__ b1, float* __restrict__ hbuf)
{
    __shared__ float4 AB[2][4][32];           // [head][wave][pair]=(offA,wA,offB,wB)
    const int wave = threadIdx.x >> 6;
    const int lane = threadIdx.x & 63;
    const int node = (blockIdx.x * 256 + threadIdx.x) >> 6;
    if (node >= N_NODES) return;
    const int2 span = rowspan[node];
    const int head = lane >> 5;

    const float2 ald  = *reinterpret_cast<const float2*>(&al_d[node * 2]);
    const float2 als0 = *reinterpret_cast<const float2*>(&al_s[node * 2]);
    const float w0h0 = lrelu_exp(als0.x + ald.x);
    const float w0h1 = lrelu_exp(als0.y + ald.y);
    const float wself = head ? w0h1 : w0h0;

    const unsigned int su = xw1u[node * 64 + lane];
    fv2 accX = { wself * bflo(su), wself * bfhi(su) };
    fv2 accY = { 0.f, 0.f };
    float dv0 = 0.f, dv1 = 0.f;
    const float4* ABh = AB[head][wave];

    for (int base = span.x; base < span.y; base += 64) {
        const int rem = span.y - base;
        const int m = rem < 64 ? rem : 64;
        const int mp = (m + 1) & ~1;
        if (lane < m) {
            const int s = sorted_src[base + lane];
            const float2 als = *reinterpret_cast<const float2*>(&al_s[s * 2]);
            const float w0 = lrelu_exp(als.x + ald.x);
            const float w1 = lrelu_exp(als.y + ald.y);
            dv0 += w0; dv1 += w1;
            const float offf = __int_as_float(s << 6);
            ((float2*)&AB[0][wave][lane >> 1])[lane & 1] = make_float2(offf, w0);
            ((float2*)&AB[1][wave][lane >> 1])[lane & 1] = make_float2(offf, w1);
        } else if (lane < mp) {
            const float offf = __int_as_float(node << 6);
            ((float2*)&AB[0][wave][lane >> 1])[lane & 1] = make_float2(offf, 0.f);
            ((float2*)&AB[1][wave][lane >> 1])[lane & 1] = make_float2(offf, 0.f);
        }
        const int P = mp >> 1;
        int p = 0;
        for (; p + 4 <= P; p += 4) {
            const float4 q0 = ABh[p + 0];
            const float4 q1 = ABh[p + 1];
            const float4 q2 = ABh[p + 2];
            const float4 q3 = ABh[p + 3];
            const unsigned int a0 = xw1u[__float_as_int(q0.x) + lane];
            const unsigned int b0 = xw1u[__float_as_int(q0.z) + lane];
            const unsigned int a1 = xw1u[__float_as_int(q1.x) + lane];
            const unsigned int b1v = xw1u[__float_as_int(q1.z) + lane];
            const unsigned int a2 = xw1u[__float_as_int(q2.x) + lane];
            const unsigned int b2 = xw1u[__float_as_int(q2.z) + lane];
            const unsigned int a3 = xw1u[__float_as_int(q3.x) + lane];
            const unsigned int b3 = xw1u[__float_as_int(q3.z) + lane];
            fv2 f;
            f.x = bflo(a0); f.y = bfhi(a0); accX += f * q0.y;
            f.x = bflo(b0); f.y = bfhi(b0); accY += f * q0.w;
            f.x = bflo(a1); f.y = bfhi(a1); accX += f * q1.y;
            f.x = bflo(b1v); f.y = bfhi(b1v); accY += f * q1.w;
            f.x = bflo(a2); f.y = bfhi(a2); accX += f * q2.y;
            f.x = bflo(b2); f.y = bfhi(b2); accY += f * q2.w;
            f.x = bflo(a3); f.y = bfhi(a3); accX += f * q3.y;
            f.x = bflo(b3); f.y = bfhi(b3); accY += f * q3.w;
        }
        for (; p < P; ++p) {
            const float4 q = ABh[p];
            const unsigned int a = xw1u[__float_as_int(q.x) + lane];
            const unsigned int b = xw1u[__float_as_int(q.z) + lane];
            fv2 f;
            f.x = bflo(a); f.y = bfhi(a); accX += f * q.y;
            f.x = bflo(b); f.y = bfhi(b); accY += f * q.w;
        }
    }
    accX += accY;
    #pragma unroll
    for (int off = 32; off; off >>= 1) {
        dv0 += __shfl_xor(dv0, off);
        dv1 += __shfl_xor(dv1, off);
    }
    const float den = head ? (dv1 + w0h1) : (dv0 + w0h0);
    const float2 bv = *reinterpret_cast<const float2*>(&b1[2 * lane]);
    float o0 = accX.x / den + bv.x;
    float o1 = accX.y / den + bv.y;
    o0 = o0 > 0.f ? o0 : 0.f;
    o1 = o1 > 0.f ? o1 : 0.f;
    *reinterpret_cast<float2*>(&hbuf[node * 128 + 2 * lane]) = make_float2(o0, o1);
}

// ---------------------------------------------------------------------------
// Layer 2 node pre-pass (register-tiled): xw2b = bf16(h @ W2) [N,64].
// sh padded to stride 132 (16B-aligned rows) -> float4 reads over k.
// ---------------------------------------------------------------------------
__global__ __launch_bounds__(256) void k_node2(
    const float* __restrict__ hbuf, const float* __restrict__ W2,
    const float* __restrict__ a_src, const float* __restrict__ a_dst,
    unsigned short* __restrict__ xw2b, float* __restrict__ al_s, float* __restrict__ al_d)
{
    __shared__ __align__(16) float sW[128 * 64];
    __shared__ __align__(16) float sh[64 * 132];
    __shared__ float sas[64], sad[64];
    const int tid = threadIdx.x;
    for (int i = tid; i < 128 * 64; i += 256) sW[i] = W2[i];
    if (tid < 64) { sas[tid] = a_src[tid]; sad[tid] = a_dst[tid]; }
    const int n0 = blockIdx.x * 64;
    for (int i = tid; i < 64 * 32; i += 256) {
        const int n = i >> 5, c4 = i & 31;
        float4 v = make_float4(0.f, 0.f, 0.f, 0.f);
        if (n0 + n < N_NODES)
            v = reinterpret_cast<const float4*>(&hbuf[(long)(n0 + n) * 128])[c4];
        *reinterpret_cast<float4*>(&sh[n * 132 + 4 * c4]) = v;
    }
    __syncthreads();

    const int tc = tid & 15, tn = tid >> 4;
    float acc[4][4] = {{0.f}};
    for (int k = 0; k < 128; k += 4) {
        const float4 w0 = *reinterpret_cast<const float4*>(&sW[(k + 0) * 64 + 4 * tc]);
        const float4 w1 = *reinterpret_cast<const float4*>(&sW[(k + 1) * 64 + 4 * tc]);
        const float4 w2 = *reinterpret_cast<const float4*>(&sW[(k + 2) * 64 + 4 * tc]);
        const float4 w3 = *reinterpret_cast<const float4*>(&sW[(k + 3) * 64 + 4 * tc]);
        #pragma unroll
        for (int j = 0; j < 4; ++j) {
            const float4 h4 = *reinterpret_cast<const float4*>(&sh[(4 * tn + j) * 132 + k]);
            acc[j][0] += h4.x * w0.x + h4.y * w1.x + h4.z * w2.x + h4.w * w3.x;
            acc[j][1] += h4.x * w0.y + h4.y * w1.y + h4.z * w2.y + h4.w * w3.y;
            acc[j][2] += h4.x * w0.z + h4.y * w1.z + h4.z * w2.z + h4.w * w3.z;
            acc[j][3] += h4.x * w0.w + h4.y * w1.w + h4.z * w2.w + h4.w * w3.w;
        }
    }
    #pragma unroll
    for (int j = 0; j < 4; ++j) {
        const int node = n0 + 4 * tn + j;
        float ps = 0.f, pd = 0.f;
        #pragma unroll
        for (int c = 0; c < 4; ++c) {
            ps += acc[j][c] * sas[4 * tc + c];
            pd += acc[j][c] * sad[4 * tc + c];
        }
        #pragma unroll
        for (int off = 1; off < 16; off <<= 1) {
            ps += __shfl_xor(ps, off);
            pd += __shfl_xor(pd, off);
        }
        if (node < N_NODES) {
            if (tc == 0) { al_s[node] = ps; al_d[node] = pd; }
            ushort4 u;
            u.x = f2bf(acc[j][0]); u.y = f2bf(acc[j][1]);
            u.z = f2bf(acc[j][2]); u.w = f2bf(acc[j][3]);
            *reinterpret_cast<ushort4*>(&xw2b[node * 64 + 4 * tc]) = u;
        }
    }
}

// ---------------------------------------------------------------------------
// Layer 2 gather: half-wave per edge pair (4 edges/step), pair-packed
// (offset,weight) LDS, fv2 accumulators. out = acc/den + b2.
// ---------------------------------------------------------------------------
__global__ __launch_bounds__(256) void k_gather2(
    const int2* __restrict__ rowspan, const int* __restrict__ sorted_src,
    const unsigned int* __restrict__ xw2u,    // 32 uints per row
    const float* __restrict__ al_s, const float* __restrict__ al_d,
    const float* __restrict__ b2, float* __restrict__ out)
{
    __shared__ float4 AB[4][32];              // [wave][pair]=(offA,wA,offB,wB)
    const int wave = threadIdx.x >> 6;
    const int lane = threadIdx.x & 63;
    const int node = (blockIdx.x * 256 + threadIdx.x) >> 6;
    if (node >= N_NODES) return;
    const int2 span = rowspan[node];
    const int li = lane & 31, hsel = lane >> 5;

    const float ald = al_d[node];
    const float w0s = lrelu_exp(al_s[node] + ald);
    const unsigned int su = xw2u[node * 32 + li];
    const float wself = hsel ? 0.f : w0s;
    fv2 acc = { wself * bflo(su), wself * bfhi(su) };
    float dv = 0.f;
    const float4* ABw = AB[wave];

    for (int base = span.x; base < span.y; base += 64) {
        const int rem = span.y - base;
        const int m = rem < 64 ? rem : 64;
        const int mp = (m + 3) & ~3;
        if (lane < m) {
            const int s = sorted_src[base + lane];
            const float w = lrelu_exp(al_s[s] + ald);
            dv += w;
            ((float2*)&AB[wave][lane >> 1])[lane & 1] =
                make_float2(__int_as_float(s << 5), w);
        } else if (lane < mp) {
            ((float2*)&AB[wave][lane >> 1])[lane & 1] =
                make_float2(__int_as_float(node << 5), 0.f);
        }
        const int P = mp >> 1;                // even
        int p = hsel;
        for (; p + 2 < P; p += 4) {
            const float4 qA = ABw[p];
            const float4 qB = ABw[p + 2];
            const unsigned int aA = xw2u[__float_as_int(qA.x) + li];
            const unsigned int bA = xw2u[__float_as_int(qA.z) + li];
            const unsigned int aB = xw2u[__float_as_int(qB.x) + li];
            const unsigned int bB = xw2u[__float_as_int(qB.z) + li];
            fv2 f;
            f.x = bflo(aA); f.y = bfhi(aA); acc += f * qA.y;
            f.x = bflo(bA); f.y = bfhi(bA); acc += f * qA.w;
            f.x = bflo(aB); f.y = bfhi(aB); acc += f * qB.y;
            f.x = bflo(bB); f.y = bfhi(bB); acc += f * qB.w;
        }
        for (; p < P; p += 2) {
            const float4 q = ABw[p];
            const unsigned int a = xw2u[__float_as_int(q.x) + li];
            const unsigned int b = xw2u[__float_as_int(q.z) + li];
            fv2 f;
            f.x = bflo(a); f.y = bfhi(a); acc += f * q.y;
            f.x = bflo(b); f.y = bfhi(b); acc += f * q.w;
        }
    }
    acc.x += __shfl_xor(acc.x, 32);
    acc.y += __shfl_xor(acc.y, 32);
    #pragma unroll
    for (int off = 32; off; off >>= 1) dv += __shfl_xor(dv, off);
    if (lane < 32) {
        const float den = dv + w0s;
        const float2 bv = *reinterpret_cast<const float2*>(&b2[2 * li]);
        *reinterpret_cast<float2*>(&out[node * 64 + 2 * li]) =
            make_float2(acc.x / den + bv.x, acc.y / den + bv.y);
    }
}

extern "C" void kernel_launch(void* const* d_in, const int* in_sizes, int n_in,
                              void* d_out, int out_size, void* d_ws, size_t ws_size,
                              hipStream_t stream)
{
    const float* x   = (const float*)d_in[0];
    const int*   ei  = (const int*)d_in[1];
    const float* W1  = (const float*)d_in[2];
    const float* as1 = (const float*)d_in[3];
    const float* ad1 = (const float*)d_in[4];
    const float* b1  = (const float*)d_in[5];
    const float* W2  = (const float*)d_in[6];
    const float* as2 = (const float*)d_in[7];
    const float* ad2 = (const float*)d_in[8];
    const float* b2  = (const float*)d_in[9];
    float* out = (float*)d_out;

    const int* srcA = ei;
    const int* dstA = ei + E_EDGES;

    // Workspace layout (bytes). Total 54,251,648 B.
    char* ws = (char*)d_ws;
    int2*  rowspan    = (int2*)(ws);                         // 400 KB (pad 409,600)
    int*   sorted_src = (int*)(ws + 409600);                 // 7.84 MB
    int*   gcur       = (int*)(ws + 8249600);                // NB ints (pad 2 KB)
    float* al_s1      = (float*)(ws + 8251648);              // 400 KB
    float* al_d1      = (float*)(ws + 8651648);              // 400 KB
    float* al_s2      = (float*)(ws + 9051648);              // 200 KB
    float* al_d2      = (float*)(ws + 9251648);              // 200 KB
    unsigned short* xw1b = (unsigned short*)(ws + 9451648);  // 12.8 MB bf16
    float* hbuf       = (float*)(ws + 22251648);             // 25.6 MB fp32
    unsigned int* binned = (unsigned int*)hbuf;              // alias: dead before gather1
    unsigned short* xw2b = (unsigned short*)(ws + 47851648); // 6.4 MB bf16

    hipMemsetAsync(gcur, 0, NB * sizeof(int), stream);
    hipLaunchKernelGGL(k_bin_node1, dim3(NBB + (N_NODES + GNPB - 1) / GNPB), dim3(768), 0, stream,
                       srcA, dstA, gcur, binned,
                       x, W1, as1, ad1, xw1b, al_s1, al_d1);
    hipLaunchKernelGGL(k_fine, dim3(NB), dim3(1024), 0, stream,
                       gcur, binned, rowspan, sorted_src);
    hipLaunchKernelGGL(k_gather1, dim3((N_NODES + 3) / 4), dim3(256), 0, stream,
                       rowspan, sorted_src, (const unsigned int*)xw1b,
                       al_s1, al_d1, b1, hbuf);
    hipLaunchKernelGGL(k_node2, dim3((N_NODES + 63) / 64), dim3(256), 0, stream,
                       hbuf, W2, as2, ad2, xw2b, al_s2, al_d2);
    hipLaunchKernelGGL(k_gather2, dim3((N_NODES + 3) / 4), dim3(256), 0, stream,
                       rowspan, sorted_src, (const unsigned int*)xw2b,
                       al_s2, al_d2, b2, out);
}

// Round 15
// 251.474 us; speedup vs baseline: 1.3722x; 1.3722x over previous
//
#include <hip/hip_runtime.h>
#include <math.h>

#define N_NODES 50000
#define E_EDGES 1600000
#define IN_CH   34
#define NEG     0.2f
#define NB      196          // coarse buckets: dst>>8
#define CAP     10000        // bucket capacity (E[8163], sigma~90)
#define EPB     8192         // edges per bin block (%4==0)
#define NBB     196          // ceil(E_EDGES / EPB)

typedef __attribute__((ext_vector_type(2))) float fv2;

static __device__ __forceinline__ unsigned short f2bf(float f) {
    unsigned int u = __float_as_uint(f);
    u += 0x7fffu + ((u >> 16) & 1u);
    return (unsigned short)(u >> 16);
}
static __device__ __forceinline__ float bflo(unsigned int u) {
    return __uint_as_float(u << 16);
}
static __device__ __forceinline__ float bfhi(unsigned int u) {
    return __uint_as_float(u & 0xffff0000u);
}
static __device__ __forceinline__ float lrelu_exp(float e) {
    return __expf(e > 0.f ? e : NEG * e);   // v_exp_f32 path, not libm
}

// Exclusive scan over 256 values held by the first 256 threads of a block
// with >=256 threads (all threads must call; contains barriers).
static __device__ __forceinline__ int scan256_wide(int v, int* wsum) {
    const int lane = threadIdx.x & 63, wv = threadIdx.x >> 6;
    int x = v;
    #pragma unroll
    for (int off = 1; off < 64; off <<= 1) {
        int y = __shfl_up(x, off);
        if (lane >= off) x += y;
    }
    if (wv < 4 && lane == 63) wsum[wv] = x;
    __syncthreads();
    if (threadIdx.x < 4) {
        int s = wsum[threadIdx.x];
        #pragma unroll
        for (int off = 1; off < 4; off <<= 1) {
            int y = __shfl_up(s, off);
            if ((int)threadIdx.x >= off) s += y;
        }
        wsum[threadIdx.x] = s;
    }
    __syncthreads();
    const int woff = (wv >= 1 && wv < 4) ? wsum[wv - 1] : 0;
    return woff + x - v;
}

// 256-thread block exclusive scan (for k_node1-free kernels not needed; kept
// only where 256-thread blocks scan — none now). (Removed.)

// ---------------------------------------------------------------------------
// Coarse binning, standalone: 196 blocks x 1024 threads (16 waves at the
// LDS-atomic-unit floor, ~28us measured in r6). Register-lean (~32 VGPR) so
// the wide-launch 64-VGPR clamp (r5/r12/r13/r14) is harmless.
// gcur must be zeroed beforehand.
// ---------------------------------------------------------------------------
__global__ __launch_bounds__(1024) void k_bin(
    const int* __restrict__ srcA, const int* __restrict__ dstA,
    int* __restrict__ gcur, unsigned int* __restrict__ binned)
{
    __shared__ unsigned int raw[8192];    // 32 KB
    __shared__ unsigned int ebuf[8192];   // 32 KB
    __shared__ int cnt[256], loff[256], lcur[256], cur[256];
    __shared__ int wsum[4];
    const int tid = threadIdx.x;
    const int base = blockIdx.x * EPB;
    const int mE = min(EPB, E_EDGES - base);   // %4 == 0
    const int nq = mE >> 2;
    if (tid < 256) cnt[tid] = 0;
    __syncthreads();
    // P1: stage packed edges + coarse histogram
    for (int q = tid; q < nq; q += 1024) {
        const int4 d4 = ((const int4*)(dstA + base))[q];
        const int4 s4 = ((const int4*)(srcA + base))[q];
        raw[4 * q + 0] = ((unsigned)d4.x << 16) | (unsigned)s4.x;
        raw[4 * q + 1] = ((unsigned)d4.y << 16) | (unsigned)s4.y;
        raw[4 * q + 2] = ((unsigned)d4.z << 16) | (unsigned)s4.z;
        raw[4 * q + 3] = ((unsigned)d4.w << 16) | (unsigned)s4.w;
        atomicAdd(&cnt[d4.x >> 8], 1);
        atomicAdd(&cnt[d4.y >> 8], 1);
        atomicAdd(&cnt[d4.z >> 8], 1);
        atomicAdd(&cnt[d4.w >> 8], 1);
    }
    __syncthreads();
    // P2: scan + global bucket cursors
    const int v = (tid < 256) ? cnt[tid] : 0;
    const int excl = scan256_wide(v, wsum);
    if (tid < 256) { loff[tid] = excl; lcur[tid] = excl; }
    if (tid < NB) cur[tid] = (v > 0) ? (tid * CAP + atomicAdd(&gcur[tid], v)) : 0;
    __syncthreads();
    // P3: LDS scatter into bucket order
    for (int p = tid; p < mE; p += 1024) {
        const unsigned int u = raw[p];
        const int q = atomicAdd(&lcur[u >> 24], 1);
        ebuf[q] = u;
    }
    __syncthreads();
    // P4: linear LDS read -> coalesced bucket-run writes
    for (int p = tid; p < mE; p += 1024) {
        const unsigned int u = ebuf[p];
        const int b = (int)(u >> 24);
        binned[cur[b] + (p - loff[b])] = u;
    }
}

// ---------------------------------------------------------------------------
// Layer 1 node GEMM, standalone 256 threads (136 VGPR — must stay narrow):
// xw1b = bf16(x @ W1), logits al_s/al_d. float4 LDS reads on both operands.
// ---------------------------------------------------------------------------
__global__ __launch_bounds__(256) void k_node1(
    const float* __restrict__ x, const float* __restrict__ W1,
    const float* __restrict__ a_src, const float* __restrict__ a_dst,
    unsigned short* __restrict__ xw1b,
    float* __restrict__ al_s, float* __restrict__ al_d)
{
    __shared__ __align__(16) float sW[IN_CH * 132];   // 17952 B
    __shared__ __align__(16) float sx[32 * 36];       // 4608 B
    __shared__ float sas[128], sad[128];
    const int tid = threadIdx.x;
    for (int i = tid; i < IN_CH * 128; i += 256) {
        int k = i >> 7, c = i & 127;
        sW[k * 132 + c] = W1[i];
    }
    if (tid < 128) { sas[tid] = a_src[tid]; sad[tid] = a_dst[tid]; }
    const int n0 = blockIdx.x * 32;
    for (int i = tid; i < 32 * IN_CH; i += 256) {
        int n = i / IN_CH;
        sx[n * 36 + (i - n * IN_CH)] = (n0 + n < N_NODES) ? x[n0 * IN_CH + i] : 0.f;
    }
    __syncthreads();

    const int tc = tid & 31, tn = tid >> 5;
    float acc[4][4] = {{0.f}};
    int k = 0;
    for (; k + 4 <= IN_CH; k += 4) {
        const float4 w0 = *reinterpret_cast<const float4*>(&sW[(k + 0) * 132 + 4 * tc]);
        const float4 w1 = *reinterpret_cast<const float4*>(&sW[(k + 1) * 132 + 4 * tc]);
        const float4 w2 = *reinterpret_cast<const float4*>(&sW[(k + 2) * 132 + 4 * tc]);
        const float4 w3 = *reinterpret_cast<const float4*>(&sW[(k + 3) * 132 + 4 * tc]);
        #pragma unroll
        for (int j = 0; j < 4; ++j) {
            const float4 h4 = *reinterpret_cast<const float4*>(&sx[(4 * tn + j) * 36 + k]);
            acc[j][0] += h4.x * w0.x + h4.y * w1.x + h4.z * w2.x + h4.w * w3.x;
            acc[j][1] += h4.x * w0.y + h4.y * w1.y + h4.z * w2.y + h4.w * w3.y;
            acc[j][2] += h4.x * w0.z + h4.y * w1.z + h4.z * w2.z + h4.w * w3.z;
            acc[j][3] += h4.x * w0.w + h4.y * w1.w + h4.z * w2.w + h4.w * w3.w;
        }
    }
    for (; k < IN_CH; ++k) {
        const float4 wv = *reinterpret_cast<const float4*>(&sW[k * 132 + 4 * tc]);
        #pragma unroll
        for (int j = 0; j < 4; ++j) {
            const float hj = sx[(4 * tn + j) * 36 + k];
            acc[j][0] += hj * wv.x; acc[j][1] += hj * wv.y;
            acc[j][2] += hj * wv.z; acc[j][3] += hj * wv.w;
        }
    }
    #pragma unroll
    for (int j = 0; j < 4; ++j) {
        const int node = n0 + 4 * tn + j;
        float ps = 0.f, pd = 0.f;
        #pragma unroll
        for (int c = 0; c < 4; ++c) {
            ps += acc[j][c] * sas[4 * tc + c];
            pd += acc[j][c] * sad[4 * tc + c];
        }
        #pragma unroll
        for (int off = 1; off < 16; off <<= 1) {
            ps += __shfl_xor(ps, off);
            pd += __shfl_xor(pd, off);
        }
        if (node < N_NODES) {
            if ((tc & 15) == 0) {
                int h = tc >> 4;
                al_s[node * 2 + h] = ps;
                al_d[node * 2 + h] = pd;
            }
            ushort4 u;
            u.x = f2bf(acc[j][0]); u.y = f2bf(acc[j][1]);
            u.z = f2bf(acc[j][2]); u.w = f2bf(acc[j][3]);
            *reinterpret_cast<ushort4*>(&xw1b[node * 128 + 4 * tc]) = u;
        }
    }
}

// ---------------------------------------------------------------------------
// Per-bucket fine sort (LDS-staged) -> sorted_src + rowspan.
// 1024 threads (16 waves, 4/SIMD) hide the LDS-atomic latency chains.
// ---------------------------------------------------------------------------
__global__ __launch_bounds__(1024) void k_fine(
    const int* __restrict__ gcur, const unsigned int* __restrict__ binned,
    int2* __restrict__ rowspan, int* __restrict__ sorted_src)
{
    __shared__ unsigned int sbin[CAP];    // 40 KB
    __shared__ int cnt[256], lcur[256];
    __shared__ int wsum[4];
    const int tid = threadIdx.x;
    const int b = blockIdx.x;
    const int bbase = b * CAP;
    const int cntb = gcur[b];
    if (tid < 256) cnt[tid] = 0;
    __syncthreads();
    for (int p = tid; p < cntb; p += 1024) {
        const unsigned int u = binned[bbase + p];
        sbin[p] = u;
        atomicAdd(&cnt[(u >> 16) & 255], 1);
    }
    __syncthreads();
    const int v = (tid < 256) ? cnt[tid] : 0;
    const int excl = scan256_wide(v, wsum);
    if (tid < 256) {
        lcur[tid] = excl;
        const int node = b * 256 + tid;
        if (node < N_NODES) rowspan[node] = make_int2(bbase + excl, bbase + excl + v);
    }
    __syncthreads();
    for (int p = tid; p < cntb; p += 1024) {
        const unsigned int u = sbin[p];
        const int q = atomicAdd(&lcur[(u >> 16) & 255], 1);
        sorted_src[bbase + q] = (int)(u & 0xffffu);
    }
}

// ---------------------------------------------------------------------------
// Layer 1 gather: one wave per node; lane owns cols 2l,2l+1 (one uint/row).
// Per-head (offset,weight) pair-packed LDS arrays -> one ds_read_b128 per
// edge pair, no per-edge selects. fv2 accumulators (packed f32 fma).
// ---------------------------------------------------------------------------
__global__ __launch_bounds__(256) void k_gather1(
    const int2* __restrict__ rowspan, const int* __restrict__ sorted_src,
    const unsigned int* __restrict__ xw1u,    // 64 uints per row
    const float* __restrict__ al_s, const float* __restrict__ al_d,
    const float* __restrict__ b1, float* __restrict__ hbuf)
{
    __shared__ float4 AB[2][4][32];           // [head][wave][pair]=(offA,wA,offB,wB)
    const int wave = threadIdx.x >> 6;
    const int lane = threadIdx.x & 63;
    const int node = (blockIdx.x * 256 + threadIdx.x) >> 6;
    if (node >= N_NODES) return;
    const int2 span = rowspan[node];
    const int head = lane >> 5;

    const float2 ald  = *reinterpret_cast<const float2*>(&al_d[node * 2]);
    const float2 als0 = *reinterpret_cast<const float2*>(&al_s[node * 2]);
    const float w0h0 = lrelu_exp(als0.x + ald.x);
    const float w0h1 = lrelu_exp(als0.y + ald.y);
    const float wself = head ? w0h1 : w0h0;

    const unsigned int su = xw1u[node * 64 + lane];
    fv2 accX = { wself * bflo(su), wself * bfhi(su) };
    fv2 accY = { 0.f, 0.f };
    float dv0 = 0.f, dv1 = 0.f;
    const float4* ABh = AB[head][wave];

    for (int base = span.x; base < span.y; base += 64) {
        const int rem = span.y - base;
        const int m = rem < 64 ? rem : 64;
        const int mp = (m + 1) & ~1;
        if (lane < m) {
            const int s = sorted_src[base + lane];
            const float2 als = *reinterpret_cast<const float2*>(&al_s[s * 2]);
            const float w0 = lrelu_exp(als.x + ald.x);
            const float w1 = lrelu_exp(als.y + ald.y);
            dv0 += w0; dv1 += w1;
            const float offf = __int_as_float(s << 6);
            ((float2*)&AB[0][wave][lane >> 1])[lane & 1] = make_float2(offf, w0);
            ((float2*)&AB[1][wave][lane >> 1])[lane & 1] = make_float2(offf, w1);
        } else if (lane < mp) {
            const float offf = __int_as_float(node << 6);
            ((float2*)&AB[0][wave][lane >> 1])[lane & 1] = make_float2(offf, 0.f);
            ((float2*)&AB[1][wave][lane >> 1])[lane & 1] = make_float2(offf, 0.f);
        }
        const int P = mp >> 1;
        int p = 0;
        for (; p + 4 <= P; p += 4) {
            const float4 q0 = ABh[p + 0];
            const float4 q1 = ABh[p + 1];
            const float4 q2 = ABh[p + 2];
            const float4 q3 = ABh[p + 3];
            const unsigned int a0 = xw1u[__float_as_int(q0.x) + lane];
            const unsigned int b0 = xw1u[__float_as_int(q0.z) + lane];
            const unsigned int a1 = xw1u[__float_as_int(q1.x) + lane];
            const unsigned int b1v = xw1u[__float_as_int(q1.z) + lane];
            const unsigned int a2 = xw1u[__float_as_int(q2.x) + lane];
            const unsigned int b2 = xw1u[__float_as_int(q2.z) + lane];
            const unsigned int a3 = xw1u[__float_as_int(q3.x) + lane];
            const unsigned int b3 = xw1u[__float_as_int(q3.z) + lane];
            fv2 f;
            f.x = bflo(a0); f.y = bfhi(a0); accX += f * q0.y;
            f.x = bflo(b0); f.y = bfhi(b0); accY += f * q0.w;
            f.x = bflo(a1); f.y = bfhi(a1); accX += f * q1.y;
            f.x = bflo(b1v); f.y = bfhi(b1v); accY += f * q1.w;
            f.x = bflo(a2); f.y = bfhi(a2); accX += f * q2.y;
            f.x = bflo(b2); f.y = bfhi(b2); accY += f * q2.w;
            f.x = bflo(a3); f.y = bfhi(a3); accX += f * q3.y;
            f.x = bflo(b3); f.y = bfhi(b3); accY += f * q3.w;
        }
        for (; p < P; ++p) {
            const float4 q = ABh[p];
            const unsigned int a = xw1u[__float_as_int(q.x) + lane];
            const unsigned int b = xw1u[__float_as_int(q.z) + lane];
            fv2 f;
            f.x = bflo(a); f.y = bfhi(a); accX += f * q.y;
            f.x = bflo(b); f.y = bfhi(b); accY += f * q.w;
        }
    }
    accX += accY;
    #pragma unroll
    for (int off = 32; off; off >>= 1) {
        dv0 += __shfl_xor(dv0, off);
        dv1 += __shfl_xor(dv1, off);
    }
    const float den = head ? (dv1 + w0h1) : (dv0 + w0h0);
    const float2 bv = *reinterpret_cast<const float2*>(&b1[2 * lane]);
    float o0 = accX.x / den + bv.x;
    float o1 = accX.y / den + bv.y;
    o0 = o0 > 0.f ? o0 : 0.f;
    o1 = o1 > 0.f ? o1 : 0.f;
    *reinterpret_cast<float2*>(&hbuf[node * 128 + 2 * lane]) = make_float2(o0, o1);
}

// ---------------------------------------------------------------------------
// Layer 2 node pre-pass (register-tiled): xw2b = bf16(h @ W2) [N,64].
// sh padded to stride 132 (16B-aligned rows) -> float4 reads over k.
// ---------------------------------------------------------------------------
__global__ __launch_bounds__(256) void k_node2(
    const float* __restrict__ hbuf, const float* __restrict__ W2,
    const float* __restrict__ a_src, const float* __restrict__ a_dst,
    unsigned short* __restrict__ xw2b, float* __restrict__ al_s, float* __restrict__ al_d)
{
    __shared__ __align__(16) float sW[128 * 64];
    __shared__ __align__(16) float sh[64 * 132];
    __shared__ float sas[64], sad[64];
    const int tid = threadIdx.x;
    for (int i = tid; i < 128 * 64; i += 256) sW[i] = W2[i];
    if (tid < 64) { sas[tid] = a_src[tid]; sad[tid] = a_dst[tid]; }
    const int n0 = blockIdx.x * 64;
    for (int i = tid; i < 64 * 32; i += 256) {
        const int n = i >> 5, c4 = i & 31;
        float4 v = make_float4(0.f, 0.f, 0.f, 0.f);
        if (n0 + n < N_NODES)
            v = reinterpret_cast<const float4*>(&hbuf[(long)(n0 + n) * 128])[c4];
        *reinterpret_cast<float4*>(&sh[n * 132 + 4 * c4]) = v;
    }
    __syncthreads();

    const int tc = tid & 15, tn = tid >> 4;
    float acc[4][4] = {{0.f}};
    for (int k = 0; k < 128; k += 4) {
        const float4 w0 = *reinterpret_cast<const float4*>(&sW[(k + 0) * 64 + 4 * tc]);
        const float4 w1 = *reinterpret_cast<const float4*>(&sW[(k + 1) * 64 + 4 * tc]);
        const float4 w2 = *reinterpret_cast<const float4*>(&sW[(k + 2) * 64 + 4 * tc]);
        const float4 w3 = *reinterpret_cast<const float4*>(&sW[(k + 3) * 64 + 4 * tc]);
        #pragma unroll
        for (int j = 0; j < 4; ++j) {
            const float4 h4 = *reinterpret_cast<const float4*>(&sh[(4 * tn + j) * 132 + k]);
            acc[j][0] += h4.x * w0.x + h4.y * w1.x + h4.z * w2.x + h4.w * w3.x;
            acc[j][1] += h4.x * w0.y + h4.y * w1.y + h4.z * w2.y + h4.w * w3.y;
            acc[j][2] += h4.x * w0.z + h4.y * w1.z + h4.z * w2.z + h4.w * w3.z;
            acc[j][3] += h4.x * w0.w + h4.y * w1.w + h4.z * w2.w + h4.w * w3.w;
        }
    }
    #pragma unroll
    for (int j = 0; j < 4; ++j) {
        const int node = n0 + 4 * tn + j;
        float ps = 0.f, pd = 0.f;
        #pragma unroll
        for (int c = 0; c < 4; ++c) {
            ps += acc[j][c] * sas[4 * tc + c];
            pd += acc[j][c] * sad[4 * tc + c];
        }
        #pragma unroll
        for (int off = 1; off < 16; off <<= 1) {
            ps += __shfl_xor(ps, off);
            pd += __shfl_xor(pd, off);
        }
        if (node < N_NODES) {
            if (tc == 0) { al_s[node] = ps; al_d[node] = pd; }
            ushort4 u;
            u.x = f2bf(acc[j][0]); u.y = f2bf(acc[j][1]);
            u.z = f2bf(acc[j][2]); u.w = f2bf(acc[j][3]);
            *reinterpret_cast<ushort4*>(&xw2b[node * 64 + 4 * tc]) = u;
        }
    }
}

// ---------------------------------------------------------------------------
// Layer 2 gather: half-wave per edge pair (4 edges/step), pair-packed
// (offset,weight) LDS, fv2 accumulators. out = acc/den + b2.
// ---------------------------------------------------------------------------
__global__ __launch_bounds__(256) void k_gather2(
    const int2* __restrict__ rowspan, const int* __restrict__ sorted_src,
    const unsigned int* __restrict__ xw2u,    // 32 uints per row
    const float* __restrict__ al_s, const float* __restrict__ al_d,
    const float* __restrict__ b2, float* __restrict__ out)
{
    __shared__ float4 AB[4][32];              // [wave][pair]=(offA,wA,offB,wB)
    const int wave = threadIdx.x >> 6;
    const int lane = threadIdx.x & 63;
    const int node = (blockIdx.x * 256 + threadIdx.x) >> 6;
    if (node >= N_NODES) return;
    const int2 span = rowspan[node];
    const int li = lane & 31, hsel = lane >> 5;

    const float ald = al_d[node];
    const float w0s = lrelu_exp(al_s[node] + ald);
    const unsigned int su = xw2u[node * 32 + li];
    const float wself = hsel ? 0.f : w0s;
    fv2 acc = { wself * bflo(su), wself * bfhi(su) };
    float dv = 0.f;
    const float4* ABw = AB[wave];

    for (int base = span.x; base < span.y; base += 64) {
        const int rem = span.y - base;
        const int m = rem < 64 ? rem : 64;
        const int mp = (m + 3) & ~3;
        if (lane < m) {
            const int s = sorted_src[base + lane];
            const float w = lrelu_exp(al_s[s] + ald);
            dv += w;
            ((float2*)&AB[wave][lane >> 1])[lane & 1] =
                make_float2(__int_as_float(s << 5), w);
        } else if (lane < mp) {
            ((float2*)&AB[wave][lane >> 1])[lane & 1] =
                make_float2(__int_as_float(node << 5), 0.f);
        }
        const int P = mp >> 1;                // even
        int p = hsel;
        for (; p + 2 < P; p += 4) {
            const float4 qA = ABw[p];
            const float4 qB = ABw[p + 2];
            const unsigned int aA = xw2u[__float_as_int(qA.x) + li];
            const unsigned int bA = xw2u[__float_as_int(qA.z) + li];
            const unsigned int aB = xw2u[__float_as_int(qB.x) + li];
            const unsigned int bB = xw2u[__float_as_int(qB.z) + li];
            fv2 f;
            f.x = bflo(aA); f.y = bfhi(aA); acc += f * qA.y;
            f.x = bflo(bA); f.y = bfhi(bA); acc += f * qA.w;
            f.x = bflo(aB); f.y = bfhi(aB); acc += f * qB.y;
            f.x = bflo(bB); f.y = bfhi(bB); acc += f * qB.w;
        }
        for (; p < P; p += 2) {
            const float4 q = ABw[p];
            const unsigned int a = xw2u[__float_as_int(q.x) + li];
            const unsigned int b = xw2u[__float_as_int(q.z) + li];
            fv2 f;
            f.x = bflo(a); f.y = bfhi(a); acc += f * q.y;
            f.x = bflo(b); f.y = bfhi(b); acc += f * q.w;
        }
    }
    acc.x += __shfl_xor(acc.x, 32);
    acc.y += __shfl_xor(acc.y, 32);
    #pragma unroll
    for (int off = 32; off; off >>= 1) dv += __shfl_xor(dv, off);
    if (lane < 32) {
        const float den = dv + w0s;
        const float2 bv = *reinterpret_cast<const float2*>(&b2[2 * li]);
        *reinterpret_cast<float2*>(&out[node * 64 + 2 * li]) =
            make_float2(acc.x / den + bv.x, acc.y / den + bv.y);
    }
}

extern "C" void kernel_launch(void* const* d_in, const int* in_sizes, int n_in,
                              void* d_out, int out_size, void* d_ws, size_t ws_size,
                              hipStream_t stream)
{
    const float* x   = (const float*)d_in[0];
    const int*   ei  = (const int*)d_in[1];
    const float* W1  = (const float*)d_in[2];
    const float* as1 = (const float*)d_in[3];
    const float* ad1 = (const float*)d_in[4];
    const float* b1  = (const float*)d_in[5];
    const float* W2  = (const float*)d_in[6];
    const float* as2 = (const float*)d_in[7];
    const float* ad2 = (const float*)d_in[8];
    const float* b2  = (const float*)d_in[9];
    float* out = (float*)d_out;

    const int* srcA = ei;
    const int* dstA = ei + E_EDGES;

    // Workspace layout (bytes). Total 54,251,648 B.
    char* ws = (char*)d_ws;
    int2*  rowspan    = (int2*)(ws);                         // 400 KB (pad 409,600)
    int*   sorted_src = (int*)(ws + 409600);                 // 7.84 MB
    int*   gcur       = (int*)(ws + 8249600);                // NB ints (pad 2 KB)
    float* al_s1      = (float*)(ws + 8251648);              // 400 KB
    float* al_d1      = (float*)(ws + 8651648);              // 400 KB
    float* al_s2      = (float*)(ws + 9051648);              // 200 KB
    float* al_d2      = (float*)(ws + 9251648);              // 200 KB
    unsigned short* xw1b = (unsigned short*)(ws + 9451648);  // 12.8 MB bf16
    float* hbuf       = (float*)(ws + 22251648);             // 25.6 MB fp32
    unsigned int* binned = (unsigned int*)hbuf;              // alias: dead before gather1
    unsigned short* xw2b = (unsigned short*)(ws + 47851648); // 6.4 MB bf16

    hipMemsetAsync(gcur, 0, NB * sizeof(int), stream);
    hipLaunchKernelGGL(k_bin, dim3(NBB), dim3(1024), 0, stream,
                       srcA, dstA, gcur, binned);
    hipLaunchKernelGGL(k_node1, dim3((N_NODES + 31) / 32), dim3(256), 0, stream,
                       x, W1, as1, ad1, xw1b, al_s1, al_d1);
    hipLaunchKernelGGL(k_fine, dim3(NB), dim3(1024), 0, stream,
                       gcur, binned, rowspan, sorted_src);
    hipLaunchKernelGGL(k_gather1, dim3((N_NODES + 3) / 4), dim3(256), 0, stream,
                       rowspan, sorted_src, (const unsigned int*)xw1b,
                       al_s1, al_d1, b1, hbuf);
    hipLaunchKernelGGL(k_node2, dim3((N_NODES + 63) / 64), dim3(256), 0, stream,
                       hbuf, W2, as2, ad2, xw2b, al_s2, al_d2);
    hipLaunchKernelGGL(k_gather2, dim3((N_NODES + 3) / 4), dim3(256), 0, stream,
                       rowspan, sorted_src, (const unsigned int*)xw2b,
                       al_s2, al_d2, b2, out);
}

// Round 16
// 250.522 us; speedup vs baseline: 1.3774x; 1.0038x over previous
//
#include <hip/hip_runtime.h>
#include <math.h>

#define N_NODES 50000
#define E_EDGES 1600000
#define IN_CH   34
#define NEG     0.2f
#define NB      196          // coarse buckets: dst>>8
#define CAP     10000        // bucket capacity (E[8163], sigma~90)
#define EPB     4096         // edges per bin block (%4==0)
#define NBB     391          // ceil(E_EDGES / EPB)

typedef __attribute__((ext_vector_type(2))) float fv2;

static __device__ __forceinline__ unsigned short f2bf(float f) {
    unsigned int u = __float_as_uint(f);
    u += 0x7fffu + ((u >> 16) & 1u);
    return (unsigned short)(u >> 16);
}
static __device__ __forceinline__ float bflo(unsigned int u) {
    return __uint_as_float(u << 16);
}
static __device__ __forceinline__ float bfhi(unsigned int u) {
    return __uint_as_float(u & 0xffff0000u);
}
static __device__ __forceinline__ float lrelu_exp(float e) {
    return __expf(e > 0.f ? e : NEG * e);   // v_exp_f32 path, not libm
}

// 256-thread block exclusive scan. wsum = int[4] LDS scratch.
static __device__ __forceinline__ int scan256_excl(int v, int* wsum) {
    const int lane = threadIdx.x & 63, wv = threadIdx.x >> 6;
    int x = v;
    #pragma unroll
    for (int off = 1; off < 64; off <<= 1) {
        int y = __shfl_up(x, off);
        if (lane >= off) x += y;
    }
    if (lane == 63) wsum[wv] = x;
    __syncthreads();
    if (threadIdx.x < 4) {
        int s = wsum[threadIdx.x];
        #pragma unroll
        for (int off = 1; off < 4; off <<= 1) {
            int y = __shfl_up(s, off);
            if ((int)threadIdx.x >= off) s += y;
        }
        wsum[threadIdx.x] = s;
    }
    __syncthreads();
    const int woff = wv ? wsum[wv - 1] : 0;
    return woff + x - v;
}

// Exclusive scan over 256 values in a 1024-thread block (all threads call).
static __device__ __forceinline__ int scan256_1024(int v, int* wsum) {
    const int lane = threadIdx.x & 63, wv = threadIdx.x >> 6;
    int x = v;
    #pragma unroll
    for (int off = 1; off < 64; off <<= 1) {
        int y = __shfl_up(x, off);
        if (lane >= off) x += y;
    }
    if (wv < 4 && lane == 63) wsum[wv] = x;
    __syncthreads();
    if (threadIdx.x < 4) {
        int s = wsum[threadIdx.x];
        #pragma unroll
        for (int off = 1; off < 4; off <<= 1) {
            int y = __shfl_up(s, off);
            if ((int)threadIdx.x >= off) s += y;
        }
        wsum[threadIdx.x] = s;
    }
    __syncthreads();
    const int woff = (wv >= 1 && wv < 4) ? wsum[wv - 1] : 0;
    return woff + x - v;
}

// ---------------------------------------------------------------------------
// Fused: blocks [0,NBB) bin 4096 edges each into bucket-strided `binned`;
// blocks [NBB,..) run the layer-1 node GEMM (float4 LDS reads on both
// operands: sx padded to stride 36 so 4-k chunks read b128).
// gcur must be zeroed beforehand.
// ---------------------------------------------------------------------------
__global__ __launch_bounds__(256) void k_bin_node1(
    const int* __restrict__ srcA, const int* __restrict__ dstA,
    int* __restrict__ gcur, unsigned int* __restrict__ binned,
    const float* __restrict__ x, const float* __restrict__ W1,
    const float* __restrict__ a_src, const float* __restrict__ a_dst,
    unsigned short* __restrict__ xw1b,
    float* __restrict__ al_s, float* __restrict__ al_d)
{
    __shared__ __align__(16) char sm[36880];
    const int tid = threadIdx.x;

    if (blockIdx.x < NBB) {
        // ---- binning role ----
        unsigned int* raw  = (unsigned int*)sm;            // 16384 B
        unsigned int* ebuf = (unsigned int*)(sm + 16384);  // 16384 B
        int* cnt  = (int*)(sm + 32768);
        int* loff = (int*)(sm + 33792);
        int* lcur = (int*)(sm + 34816);
        int* cur  = (int*)(sm + 35840);
        int* wsum = (int*)(sm + 36864);
        cnt[tid] = 0;
        __syncthreads();
        const int base = blockIdx.x * EPB;
        const int mE = min(EPB, E_EDGES - base);           // %4 == 0
        const int nq = mE >> 2;
        for (int q = tid; q < nq; q += 256) {
            const int4 d4 = ((const int4*)(dstA + base))[q];
            const int4 s4 = ((const int4*)(srcA + base))[q];
            raw[4 * q + 0] = ((unsigned)d4.x << 16) | (unsigned)s4.x;
            raw[4 * q + 1] = ((unsigned)d4.y << 16) | (unsigned)s4.y;
            raw[4 * q + 2] = ((unsigned)d4.z << 16) | (unsigned)s4.z;
            raw[4 * q + 3] = ((unsigned)d4.w << 16) | (unsigned)s4.w;
            atomicAdd(&cnt[d4.x >> 8], 1);
            atomicAdd(&cnt[d4.y >> 8], 1);
            atomicAdd(&cnt[d4.z >> 8], 1);
            atomicAdd(&cnt[d4.w >> 8], 1);
        }
        __syncthreads();
        const int v = cnt[tid];
        const int excl = scan256_excl(v, wsum);
        loff[tid] = excl;
        lcur[tid] = excl;
        cur[tid] = (tid < NB && v > 0) ? (tid * CAP + atomicAdd(&gcur[tid], v)) : 0;
        __syncthreads();
        for (int p = tid; p < mE; p += 256) {
            const unsigned int u = raw[p];
            const int q = atomicAdd(&lcur[u >> 24], 1);
            ebuf[q] = u;
        }
        __syncthreads();
        for (int p = tid; p < mE; p += 256) {
            const unsigned int u = ebuf[p];
            const int b = (int)(u >> 24);
            binned[cur[b] + (p - loff[b])] = u;
        }
    } else {
        // ---- node1 role: xw1b = bf16(x @ W1), logits al_s/al_d ----
        float* sW  = (float*)sm;                 // 34*132*4 = 17952 B
        float* sx  = (float*)(sm + 17952);       // 32*36*4  = 4608 B
        float* sas = (float*)(sm + 22560);       // 512 B
        float* sad = (float*)(sm + 23072);       // 512 B -> 23584 total
        for (int i = tid; i < IN_CH * 128; i += 256) {
            int k = i >> 7, c = i & 127;
            sW[k * 132 + c] = W1[i];
        }
        if (tid < 128) { sas[tid] = a_src[tid]; sad[tid] = a_dst[tid]; }
        const int n0 = (blockIdx.x - NBB) * 32;
        for (int i = tid; i < 32 * IN_CH; i += 256) {
            int n = i / IN_CH;
            sx[n * 36 + (i - n * IN_CH)] = (n0 + n < N_NODES) ? x[n0 * IN_CH + i] : 0.f;
        }
        __syncthreads();

        const int tc = tid & 31, tn = tid >> 5;
        float acc[4][4] = {{0.f}};
        int k = 0;
        for (; k + 4 <= IN_CH; k += 4) {
            const float4 w0 = *reinterpret_cast<const float4*>(&sW[(k + 0) * 132 + 4 * tc]);
            const float4 w1 = *reinterpret_cast<const float4*>(&sW[(k + 1) * 132 + 4 * tc]);
            const float4 w2 = *reinterpret_cast<const float4*>(&sW[(k + 2) * 132 + 4 * tc]);
            const float4 w3 = *reinterpret_cast<const float4*>(&sW[(k + 3) * 132 + 4 * tc]);
            #pragma unroll
            for (int j = 0; j < 4; ++j) {
                const float4 h4 = *reinterpret_cast<const float4*>(&sx[(4 * tn + j) * 36 + k]);
                acc[j][0] += h4.x * w0.x + h4.y * w1.x + h4.z * w2.x + h4.w * w3.x;
                acc[j][1] += h4.x * w0.y + h4.y * w1.y + h4.z * w2.y + h4.w * w3.y;
                acc[j][2] += h4.x * w0.z + h4.y * w1.z + h4.z * w2.z + h4.w * w3.z;
                acc[j][3] += h4.x * w0.w + h4.y * w1.w + h4.z * w2.w + h4.w * w3.w;
            }
        }
        for (; k < IN_CH; ++k) {
            const float4 wv = *reinterpret_cast<const float4*>(&sW[k * 132 + 4 * tc]);
            #pragma unroll
            for (int j = 0; j < 4; ++j) {
                const float hj = sx[(4 * tn + j) * 36 + k];
                acc[j][0] += hj * wv.x; acc[j][1] += hj * wv.y;
                acc[j][2] += hj * wv.z; acc[j][3] += hj * wv.w;
            }
        }
        #pragma unroll
        for (int j = 0; j < 4; ++j) {
            const int node = n0 + 4 * tn + j;
            float ps = 0.f, pd = 0.f;
            #pragma unroll
            for (int c = 0; c < 4; ++c) {
                ps += acc[j][c] * sas[4 * tc + c];
                pd += acc[j][c] * sad[4 * tc + c];
            }
            #pragma unroll
            for (int off = 1; off < 16; off <<= 1) {
                ps += __shfl_xor(ps, off);
                pd += __shfl_xor(pd, off);
            }
            if (node < N_NODES) {
                if ((tc & 15) == 0) {
                    int h = tc >> 4;
                    al_s[node * 2 + h] = ps;
                    al_d[node * 2 + h] = pd;
                }
                ushort4 u;
                u.x = f2bf(acc[j][0]); u.y = f2bf(acc[j][1]);
                u.z = f2bf(acc[j][2]); u.w = f2bf(acc[j][3]);
                *reinterpret_cast<ushort4*>(&xw1b[node * 128 + 4 * tc]) = u;
            }
        }
    }
}

// ---------------------------------------------------------------------------
// Per-bucket fine sort (LDS-staged) -> sorted_src + rowspan.
// 1024 threads (16 waves, 4/SIMD) hide the LDS-atomic latency chains.
// ---------------------------------------------------------------------------
__global__ __launch_bounds__(1024) void k_fine(
    const int* __restrict__ gcur, const unsigned int* __restrict__ binned,
    int2* __restrict__ rowspan, int* __restrict__ sorted_src)
{
    __shared__ unsigned int sbin[CAP];    // 40 KB
    __shared__ int cnt[256], lcur[256];
    __shared__ int wsum[4];
    const int tid = threadIdx.x;
    const int b = blockIdx.x;
    const int bbase = b * CAP;
    const int cntb = gcur[b];
    if (tid < 256) cnt[tid] = 0;
    __syncthreads();
    for (int p = tid; p < cntb; p += 1024) {
        const unsigned int u = binned[bbase + p];
        sbin[p] = u;
        atomicAdd(&cnt[(u >> 16) & 255], 1);
    }
    __syncthreads();
    const int v = (tid < 256) ? cnt[tid] : 0;
    const int excl = scan256_1024(v, wsum);
    if (tid < 256) {
        lcur[tid] = excl;
        const int node = b * 256 + tid;
        if (node < N_NODES) rowspan[node] = make_int2(bbase + excl, bbase + excl + v);
    }
    __syncthreads();
    for (int p = tid; p < cntb; p += 1024) {
        const unsigned int u = sbin[p];
        const int q = atomicAdd(&lcur[(u >> 16) & 255], 1);
        sorted_src[bbase + q] = (int)(u & 0xffffu);
    }
}

// ---------------------------------------------------------------------------
// Layer 1 gather: one wave per node; lane owns cols 2l,2l+1 (one uint/row).
// Per-head (offset,weight) pair-packed LDS arrays -> one ds_read_b128 per
// edge pair, no per-edge selects. fv2 accumulators (packed f32 fma).
// ---------------------------------------------------------------------------
__global__ __launch_bounds__(256) void k_gather1(
    const int2* __restrict__ rowspan, const int* __restrict__ sorted_src,
    const unsigned int* __restrict__ xw1u,    // 64 uints per row
    const float* __restrict__ al_s, const float* __restrict__ al_d,
    const float* __restrict__ b1, float* __restrict__ hbuf)
{
    __shared__ float4 AB[2][4][32];           // [head][wave][pair]=(offA,wA,offB,wB)
    const int wave = threadIdx.x >> 6;
    const int lane = threadIdx.x & 63;
    const int node = (blockIdx.x * 256 + threadIdx.x) >> 6;
    if (node >= N_NODES) return;
    const int2 span = rowspan[node];
    const int head = lane >> 5;

    const float2 ald  = *reinterpret_cast<const float2*>(&al_d[node * 2]);
    const float2 als0 = *reinterpret_cast<const float2*>(&al_s[node * 2]);
    const float w0h0 = lrelu_exp(als0.x + ald.x);
    const float w0h1 = lrelu_exp(als0.y + ald.y);
    const float wself = head ? w0h1 : w0h0;

    const unsigned int su = xw1u[node * 64 + lane];
    fv2 accX = { wself * bflo(su), wself * bfhi(su) };
    fv2 accY = { 0.f, 0.f };
    float dv0 = 0.f, dv1 = 0.f;
    const float4* ABh = AB[head][wave];

    for (int base = span.x; base < span.y; base += 64) {
        const int rem = span.y - base;
        const int m = rem < 64 ? rem : 64;
        const int mp = (m + 1) & ~1;
        if (lane < m) {
            const int s = sorted_src[base + lane];
            const float2 als = *reinterpret_cast<const float2*>(&al_s[s * 2]);
            const float w0 = lrelu_exp(als.x + ald.x);
            const float w1 = lrelu_exp(als.y + ald.y);
            dv0 += w0; dv1 += w1;
            const float offf = __int_as_float(s << 6);
            ((float2*)&AB[0][wave][lane >> 1])[lane & 1] = make_float2(offf, w0);
            ((float2*)&AB[1][wave][lane >> 1])[lane & 1] = make_float2(offf, w1);
        } else if (lane < mp) {
            const float offf = __int_as_float(node << 6);
            ((float2*)&AB[0][wave][lane >> 1])[lane & 1] = make_float2(offf, 0.f);
            ((float2*)&AB[1][wave][lane >> 1])[lane & 1] = make_float2(offf, 0.f);
        }
        const int P = mp >> 1;
        int p = 0;
        for (; p + 4 <= P; p += 4) {
            const float4 q0 = ABh[p + 0];
            const float4 q1 = ABh[p + 1];
            const float4 q2 = ABh[p + 2];
            const float4 q3 = ABh[p + 3];
            const unsigned int a0 = xw1u[__float_as_int(q0.x) + lane];
            const unsigned int b0 = xw1u[__float_as_int(q0.z) + lane];
            const unsigned int a1 = xw1u[__float_as_int(q1.x) + lane];
            const unsigned int b1v = xw1u[__float_as_int(q1.z) + lane];
            const unsigned int a2 = xw1u[__float_as_int(q2.x) + lane];
            const unsigned int b2 = xw1u[__float_as_int(q2.z) + lane];
            const unsigned int a3 = xw1u[__float_as_int(q3.x) + lane];
            const unsigned int b3 = xw1u[__float_as_int(q3.z) + lane];
            fv2 f;
            f.x = bflo(a0); f.y = bfhi(a0); accX += f * q0.y;
            f.x = bflo(b0); f.y = bfhi(b0); accY += f * q0.w;
            f.x = bflo(a1); f.y = bfhi(a1); accX += f * q1.y;
            f.x = bflo(b1v); f.y = bfhi(b1v); accY += f * q1.w;
            f.x = bflo(a2); f.y = bfhi(a2); accX += f * q2.y;
            f.x = bflo(b2); f.y = bfhi(b2); accY += f * q2.w;
            f.x = bflo(a3); f.y = bfhi(a3); accX += f * q3.y;
            f.x = bflo(b3); f.y = bfhi(b3); accY += f * q3.w;
        }
        for (; p < P; ++p) {
            const float4 q = ABh[p];
            const unsigned int a = xw1u[__float_as_int(q.x) + lane];
            const unsigned int b = xw1u[__float_as_int(q.z) + lane];
            fv2 f;
            f.x = bflo(a); f.y = bfhi(a); accX += f * q.y;
            f.x = bflo(b); f.y = bfhi(b); accY += f * q.w;
        }
    }
    accX += accY;
    #pragma unroll
    for (int off = 32; off; off >>= 1) {
        dv0 += __shfl_xor(dv0, off);
        dv1 += __shfl_xor(dv1, off);
    }
    const float den = head ? (dv1 + w0h1) : (dv0 + w0h0);
    const float2 bv = *reinterpret_cast<const float2*>(&b1[2 * lane]);
    float o0 = accX.x / den + bv.x;
    float o1 = accX.y / den + bv.y;
    o0 = o0 > 0.f ? o0 : 0.f;
    o1 = o1 > 0.f ? o1 : 0.f;
    *reinterpret_cast<float2*>(&hbuf[node * 128 + 2 * lane]) = make_float2(o0, o1);
}

// ---------------------------------------------------------------------------
// Layer 2 node pre-pass (register-tiled): xw2b = bf16(h @ W2) [N,64].
// sh padded to stride 132 (16B-aligned rows) -> float4 reads over k,
// replacing 4 scalar ds_read_b32 per k with 1 ds_read_b128 per 4k.
// ---------------------------------------------------------------------------
__global__ __launch_bounds__(256) void k_node2(
    const float* __restrict__ hbuf, const float* __restrict__ W2,
    const float* __restrict__ a_src, const float* __restrict__ a_dst,
    unsigned short* __restrict__ xw2b, float* __restrict__ al_s, float* __restrict__ al_d)
{
    __shared__ __align__(16) float sW[128 * 64];
    __shared__ __align__(16) float sh[64 * 132];
    __shared__ float sas[64], sad[64];
    const int tid = threadIdx.x;
    for (int i = tid; i < 128 * 64; i += 256) sW[i] = W2[i];
    if (tid < 64) { sas[tid] = a_src[tid]; sad[tid] = a_dst[tid]; }
    const int n0 = blockIdx.x * 64;
    for (int i = tid; i < 64 * 32; i += 256) {
        const int n = i >> 5, c4 = i & 31;
        float4 v = make_float4(0.f, 0.f, 0.f, 0.f);
        if (n0 + n < N_NODES)
            v = reinterpret_cast<const float4*>(&hbuf[(long)(n0 + n) * 128])[c4];
        *reinterpret_cast<float4*>(&sh[n * 132 + 4 * c4]) = v;
    }
    __syncthreads();

    const int tc = tid & 15, tn = tid >> 4;
    float acc[4][4] = {{0.f}};
    for (int k = 0; k < 128; k += 4) {
        const float4 w0 = *reinterpret_cast<const float4*>(&sW[(k + 0) * 64 + 4 * tc]);
        const float4 w1 = *reinterpret_cast<const float4*>(&sW[(k + 1) * 64 + 4 * tc]);
        const float4 w2 = *reinterpret_cast<const float4*>(&sW[(k + 2) * 64 + 4 * tc]);
        const float4 w3 = *reinterpret_cast<const float4*>(&sW[(k + 3) * 64 + 4 * tc]);
        #pragma unroll
        for (int j = 0; j < 4; ++j) {
            const float4 h4 = *reinterpret_cast<const float4*>(&sh[(4 * tn + j) * 132 + k]);
            acc[j][0] += h4.x * w0.x + h4.y * w1.x + h4.z * w2.x + h4.w * w3.x;
            acc[j][1] += h4.x * w0.y + h4.y * w1.y + h4.z * w2.y + h4.w * w3.y;
            acc[j][2] += h4.x * w0.z + h4.y * w1.z + h4.z * w2.z + h4.w * w3.z;
            acc[j][3] += h4.x * w0.w + h4.y * w1.w + h4.z * w2.w + h4.w * w3.w;
        }
    }
    #pragma unroll
    for (int j = 0; j < 4; ++j) {
        const int node = n0 + 4 * tn + j;
        float ps = 0.f, pd = 0.f;
        #pragma unroll
        for (int c = 0; c < 4; ++c) {
            ps += acc[j][c] * sas[4 * tc + c];
            pd += acc[j][c] * sad[4 * tc + c];
        }
        #pragma unroll
        for (int off = 1; off < 16; off <<= 1) {
            ps += __shfl_xor(ps, off);
            pd += __shfl_xor(pd, off);
        }
        if (node < N_NODES) {
            if (tc == 0) { al_s[node] = ps; al_d[node] = pd; }
            ushort4 u;
            u.x = f2bf(acc[j][0]); u.y = f2bf(acc[j][1]);
            u.z = f2bf(acc[j][2]); u.w = f2bf(acc[j][3]);
            *reinterpret_cast<ushort4*>(&xw2b[node * 64 + 4 * tc]) = u;
        }
    }
}

// ---------------------------------------------------------------------------
// Layer 2 gather: half-wave per edge pair (4 edges/step), pair-packed
// (offset,weight) LDS, fv2 accumulators. out = acc/den + b2.
// ---------------------------------------------------------------------------
__global__ __launch_bounds__(256) void k_gather2(
    const int2* __restrict__ rowspan, const int* __restrict__ sorted_src,
    const unsigned int* __restrict__ xw2u,    // 32 uints per row
    const float* __restrict__ al_s, const float* __restrict__ al_d,
    const float* __restrict__ b2, float* __restrict__ out)
{
    __shared__ float4 AB[4][32];              // [wave][pair]=(offA,wA,offB,wB)
    const int wave = threadIdx.x >> 6;
    const int lane = threadIdx.x & 63;
    const int node = (blockIdx.x * 256 + threadIdx.x) >> 6;
    if (node >= N_NODES) return;
    const int2 span = rowspan[node];
    const int li = lane & 31, hsel = lane >> 5;

    const float ald = al_d[node];
    const float w0s = lrelu_exp(al_s[node] + ald);
    const unsigned int su = xw2u[node * 32 + li];
    const float wself = hsel ? 0.f : w0s;
    fv2 acc = { wself * bflo(su), wself * bfhi(su) };
    float dv = 0.f;
    const float4* ABw = AB[wave];

    for (int base = span.x; base < span.y; base += 64) {
        const int rem = span.y - base;
        const int m = rem < 64 ? rem : 64;
        const int mp = (m + 3) & ~3;
        if (lane < m) {
            const int s = sorted_src[base + lane];
            const float w = lrelu_exp(al_s[s] + ald);
            dv += w;
            ((float2*)&AB[wave][lane >> 1])[lane & 1] =
                make_float2(__int_as_float(s << 5), w);
        } else if (lane < mp) {
            ((float2*)&AB[wave][lane >> 1])[lane & 1] =
                make_float2(__int_as_float(node << 5), 0.f);
        }
        const int P = mp >> 1;                // even
        int p = hsel;
        for (; p + 2 < P; p += 4) {
            const float4 qA = ABw[p];
            const float4 qB = ABw[p + 2];
            const unsigned int aA = xw2u[__float_as_int(qA.x) + li];
            const unsigned int bA = xw2u[__float_as_int(qA.z) + li];
            const unsigned int aB = xw2u[__float_as_int(qB.x) + li];
            const unsigned int bB = xw2u[__float_as_int(qB.z) + li];
            fv2 f;
            f.x = bflo(aA); f.y = bfhi(aA); acc += f * qA.y;
            f.x = bflo(bA); f.y = bfhi(bA); acc += f * qA.w;
            f.x = bflo(aB); f.y = bfhi(aB); acc += f * qB.y;
            f.x = bflo(bB); f.y = bfhi(bB); acc += f * qB.w;
        }
        for (; p < P; p += 2) {
            const float2 q2v = *(const float2*)&ABw[p];
            const float4 q = ABw[p];
            const unsigned int a = xw2u[__float_as_int(q.x) + li];
            const unsigned int b = xw2u[__float_as_int(q.z) + li];
            fv2 f;
            f.x = bflo(a); f.y = bfhi(a); acc += f * q.y;
            f.x = bflo(b); f.y = bfhi(b); acc += f * q.w;
            (void)q2v;
        }
    }
    acc.x += __shfl_xor(acc.x, 32);
    acc.y += __shfl_xor(acc.y, 32);
    #pragma unroll
    for (int off = 32; off; off >>= 1) dv += __shfl_xor(dv, off);
    if (lane < 32) {
        const float den = dv + w0s;
        const float2 bv = *reinterpret_cast<const float2*>(&b2[2 * li]);
        *reinterpret_cast<float2*>(&out[node * 64 + 2 * li]) =
            make_float2(acc.x / den + bv.x, acc.y / den + bv.y);
    }
}

extern "C" void kernel_launch(void* const* d_in, const int* in_sizes, int n_in,
                              void* d_out, int out_size, void* d_ws, size_t ws_size,
                              hipStream_t stream)
{
    const float* x   = (const float*)d_in[0];
    const int*   ei  = (const int*)d_in[1];
    const float* W1  = (const float*)d_in[2];
    const float* as1 = (const float*)d_in[3];
    const float* ad1 = (const float*)d_in[4];
    const float* b1  = (const float*)d_in[5];
    const float* W2  = (const float*)d_in[6];
    const float* as2 = (const float*)d_in[7];
    const float* ad2 = (const float*)d_in[8];
    const float* b2  = (const float*)d_in[9];
    float* out = (float*)d_out;

    const int* srcA = ei;
    const int* dstA = ei + E_EDGES;

    // Workspace layout (bytes). Total 54,251,648 B.
    char* ws = (char*)d_ws;
    int2*  rowspan    = (int2*)(ws);                         // 400 KB (pad 409,600)
    int*   sorted_src = (int*)(ws + 409600);                 // 7.84 MB
    int*   gcur       = (int*)(ws + 8249600);                // NB ints (pad 2 KB)
    float* al_s1      = (float*)(ws + 8251648);              // 400 KB
    float* al_d1      = (float*)(ws + 8651648);              // 400 KB
    float* al_s2      = (float*)(ws + 9051648);              // 200 KB
    float* al_d2      = (float*)(ws + 9251648);              // 200 KB
    unsigned short* xw1b = (unsigned short*)(ws + 9451648);  // 12.8 MB bf16
    float* hbuf       = (float*)(ws + 22251648);             // 25.6 MB fp32
    unsigned int* binned = (unsigned int*)hbuf;              // alias: dead before gather1
    unsigned short* xw2b = (unsigned short*)(ws + 47851648); // 6.4 MB bf16

    hipMemsetAsync(gcur, 0, NB * sizeof(int), stream);
    hipLaunchKernelGGL(k_bin_node1, dim3(NBB + (N_NODES + 31) / 32), dim3(256), 0, stream,
                       srcA, dstA, gcur, binned,
                       x, W1, as1, ad1, xw1b, al_s1, al_d1);
    hipLaunchKernelGGL(k_fine, dim3(NB), dim3(1024), 0, stream,
                       gcur, binned, rowspan, sorted_src);
    hipLaunchKernelGGL(k_gather1, dim3((N_NODES + 3) / 4), dim3(256), 0, stream,
                       rowspan, sorted_src, (const unsigned int*)xw1b,
                       al_s1, al_d1, b1, hbuf);
    hipLaunchKernelGGL(k_node2, dim3((N_NODES + 63) / 64), dim3(256), 0, stream,
                       hbuf, W2, as2, ad2, xw2b, al_s2, al_d2);
    hipLaunchKernelGGL(k_gather2, dim3((N_NODES + 3) / 4), dim3(256), 0, stream,
                       rowspan, sorted_src, (const unsigned int*)xw2b,
                       al_s2, al_d2, b2, out);
}